// Round 1
// 133.929 us; speedup vs baseline: 1.0343x; 1.0343x over previous
//
#include <hip/hip_runtime.h>
#include <hip/hip_bf16.h>

// QuIP#-style quantized linear. R11: two changes on the R10 structure.
// (a) KSPLIT 16->8: zpart 8MB->4MB (zsum reads halve), qgemm = 256 blocks
//     = exactly 1/CU (same 32768 gathers/CU -> same gather wall, cleaner
//     tail, half the zpart write traffic).
// (b) codebook gathers alternate 50/50 between the L1 path (aux=0) and the
//     sc0 L2-direct path (aux=1) by pipeline-group parity. Theory: the
//     ~46us qgemm wall is a per-CU outstanding-request cap (~64 lines x
//     ~215cy L2 latency). R6 (all-L1) and R10 (all-sc0) both cap at the
//     same rate; if the two paths track requests in independent pools,
//     alternating doubles concurrency -> qgemm ~30us. If the cap is a
//     shared downstream queue, qgemm is unchanged and only (a) pays.

typedef __attribute__((ext_vector_type(16))) float f32x16;
typedef __attribute__((ext_vector_type(8))) __bf16 bf16x8;
typedef __attribute__((ext_vector_type(4))) __bf16 bf16x4;
typedef __attribute__((ext_vector_type(4))) int i32x4;

#define IN_F 8192
#define OUT_F 8192
#define TOKENS 32
#define KSPLIT 8
#define KCHUNK 1024
#define CH (KCHUNK / 8)            // 128 16B-chunks per token row in LDS
#define GROUPS (KCHUNK / 32)       // 32 pipeline groups (4 k-groups each)
#define DG 5                       // gather lookahead (groups)
#define DI 7                       // idx lookahead (groups)
#define INV_SQRT_8192 0.011048543456039806f
#define PAD(i) ((i) + ((i) >> 5))

#if __has_builtin(__builtin_amdgcn_raw_buffer_load_b128) && \
    __has_builtin(__builtin_amdgcn_make_buffer_rsrc)
#define HAVE_BUF 1
#else
#define HAVE_BUF 0
#endif

// ---------------- register FWHT-32 ----------------
__device__ inline void fwht32_reg(float* r) {
    #pragma unroll
    for (int h = 1; h < 32; h <<= 1)
        #pragma unroll
        for (int i = 0; i < 32; i += 2 * h)
            #pragma unroll
            for (int j = 0; j < h; ++j) {
                float a = r[i + j], b = r[i + j + h];
                r[i + j] = a + b;
                r[i + j + h] = a - b;
            }
}

// ---------------- full FWHT-8192 in padded LDS, 256 threads ----------------
__device__ inline void fwht8192_lds(float* s, int tid) {
    float r[32];
    int b1 = tid * 32;                       // pass 1: bits 0-4
    #pragma unroll
    for (int j = 0; j < 32; ++j) r[j] = s[PAD(b1 + j)];
    fwht32_reg(r);
    #pragma unroll
    for (int j = 0; j < 32; ++j) s[PAD(b1 + j)] = r[j];
    __syncthreads();
    int b2 = (tid & 31) + (tid >> 5) * 1024; // pass 2: bits 5-9
    #pragma unroll
    for (int j = 0; j < 32; ++j) r[j] = s[PAD(b2 + 32 * j)];
    fwht32_reg(r);
    #pragma unroll
    for (int j = 0; j < 32; ++j) s[PAD(b2 + 32 * j)] = r[j];
    __syncthreads();
    #pragma unroll
    for (int jj = 0; jj < 4; ++jj) {         // pass 3: bits 10-12
        float g[8];
        int b3 = tid * 4 + jj;
        #pragma unroll
        for (int k = 0; k < 8; ++k) g[k] = s[PAD(b3 + 1024 * k)];
        #pragma unroll
        for (int h = 1; h < 8; h <<= 1)
            #pragma unroll
            for (int i = 0; i < 8; i += 2 * h)
                #pragma unroll
                for (int j = 0; j < h; ++j) {
                    float a = g[i + j], b = g[i + j + h];
                    g[i + j] = a + b;
                    g[i + j + h] = a - b;
                }
        #pragma unroll
        for (int k = 0; k < 8; ++k) s[PAD(b3 + 1024 * k)] = g[k];
    }
    __syncthreads();
}

// ---------------- kernel 1: codebook cvt + input FWHT ----------------
__global__ __launch_bounds__(256)
void prep_kernel(const float* __restrict__ cb, __bf16* __restrict__ cbb,
                 const float* __restrict__ x, const float* __restrict__ su,
                 __bf16* __restrict__ xh) {
    __shared__ float s[8192 + 256];
    const int tid = threadIdx.x;
    if (blockIdx.x < 512) {
        int i = blockIdx.x * 256 + tid;
        float4 v = ((const float4*)cb)[i];
        bf16x4 o;
        o[0] = (__bf16)v.x; o[1] = (__bf16)v.y;
        o[2] = (__bf16)v.z; o[3] = (__bf16)v.w;
        ((bf16x4*)cbb)[i] = o;
        return;
    }
    const int t = blockIdx.x - 512;
    #pragma unroll
    for (int i = tid; i < IN_F; i += 256)
        s[PAD(i)] = x[t * IN_F + i] * su[i];
    __syncthreads();
    fwht8192_lds(s, tid);
    #pragma unroll
    for (int i = tid; i < IN_F; i += 256)
        xh[t * IN_F + i] = (__bf16)(s[PAD(i)] * INV_SQRT_8192);
}

// ---------------- kernel 2: zpart = xh @ W^T (dual-path gathers) ----------
__global__ __launch_bounds__(512, 4)
void qgemm_kernel(const int* __restrict__ qidxs,
                  const __bf16* __restrict__ cb,
                  const __bf16* __restrict__ xh,
                  __bf16* __restrict__ zpart) {
    __shared__ __align__(16) __bf16 xt[TOKENS * KCHUNK];   // 64 KB
    const int ks = blockIdx.x & (KSPLIT - 1);
    const int nb = blockIdx.x >> 3;
    const int tid = threadIdx.x;
    const int wave = tid >> 6, lane = tid & 63;
    const int h = lane >> 5, lc = lane & 31;
    const int n = nb * 256 + wave * 32 + lc;

    // stage xh k-slice (32 tok x 1024 k) -> LDS, 16B chunks xor-swizzled
    #pragma unroll
    for (int i = 0; i < 8; ++i) {
        int f = i * 512 + tid, r = f >> 7, c = f & 127;
        i32x4 v = *(const i32x4*)(xh + (size_t)r * IN_F + ks * KCHUNK + c * 8);
        *(i32x4*)(xt + ((r * CH + (c ^ (r & 7))) << 3)) = v;
    }
    __syncthreads();    // the only barrier

    const int* qrow = qidxs + (size_t)n * (IN_F / 8) + ks * (KCHUNK / 8);

#if HAVE_BUF
    // SRD over the bf16 codebook (1 MB). aux=1 -> SC0: L1-bypass, L2-cached.
    __amdgpu_buffer_rsrc_t rsrc = __builtin_amdgcn_make_buffer_rsrc(
        (void*)cb, (short)0, 65536 * 16, 0x00020000);
    #define GA(ix, au) __builtin_bit_cast(bf16x8, \
        __builtin_amdgcn_raw_buffer_load_b128(rsrc, (ix) << 4, 0, au))
#else
    const bf16x8* cbv = (const bf16x8*)cb;
    #define GA(ix, au) (cbv[ix])
#endif

    f32x16 acc;
    #pragma unroll
    for (int i = 0; i < 16; ++i) acc[i] = 0.f;

    i32x4 iv[GROUPS];
    bf16x8 bfr[GROUPS][2];

    #pragma unroll
    for (int g = 0; g < DI; ++g)
        iv[g] = *(const i32x4*)(qrow + g * 4);
    #pragma unroll
    for (int g = 0; g < DG; ++g) {
        if (g & 1) {
            bfr[g][0] = GA(h ? iv[g][1] : iv[g][0], 1);
            bfr[g][1] = GA(h ? iv[g][3] : iv[g][2], 1);
        } else {
            bfr[g][0] = GA(h ? iv[g][1] : iv[g][0], 0);
            bfr[g][1] = GA(h ? iv[g][3] : iv[g][2], 0);
        }
    }

    #pragma unroll
    for (int g = 0; g < GROUPS; ++g) {
        if (g + DI < GROUPS)
            iv[g + DI] = *(const i32x4*)(qrow + (g + DI) * 4);
        if (g + DG < GROUPS) {
            if ((g + DG) & 1) {
                bfr[g + DG][0] = GA(h ? iv[g + DG][1] : iv[g + DG][0], 1);
                bfr[g + DG][1] = GA(h ? iv[g + DG][3] : iv[g + DG][2], 1);
            } else {
                bfr[g + DG][0] = GA(h ? iv[g + DG][1] : iv[g + DG][0], 0);
                bfr[g + DG][1] = GA(h ? iv[g + DG][3] : iv[g + DG][2], 0);
            }
        }
        #pragma unroll
        for (int sgi = 0; sgi < 2; ++sgi) {
            const int T = 2 * g + sgi;
            bf16x8 a = *(const bf16x8*)(xt +
                          ((lc * CH + ((2 * T + h) ^ (lc & 7))) << 3));
            acc = __builtin_amdgcn_mfma_f32_32x32x16_bf16(a, bfr[g][sgi],
                                                          acc, 0, 0, 0);
        }
    }

    // D[m=(r&3)+4h+8(r>>2)][n=lc] -> bf16 partials
    __bf16* zp = zpart + ((size_t)ks * TOKENS) * OUT_F + n;
    #pragma unroll
    for (int r = 0; r < 16; ++r) {
        int m = (r & 3) + 4 * h + 8 * (r >> 2);
        zp[(size_t)m * OUT_F] = (__bf16)acc[r];
    }
}

// ------- kernel 3: out = fwht(sum_ks zpart)/sqrt(n) * SV * Wscale ----------
__global__ __launch_bounds__(256)
void zsum_kernel(const __bf16* __restrict__ zpart, const float* __restrict__ sv,
                 const float* __restrict__ wscale, float* __restrict__ out) {
    __shared__ float s[8192 + 256];
    const int t = blockIdx.x, tid = threadIdx.x;
    #pragma unroll
    for (int cc = 0; cc < 4; ++cc) {
        int col = cc * 2048 + tid * 8;
        float a[8] = {0.f, 0.f, 0.f, 0.f, 0.f, 0.f, 0.f, 0.f};
        #pragma unroll
        for (int ks = 0; ks < KSPLIT; ++ks) {
            bf16x8 v = *(const bf16x8*)(zpart +
                         ((size_t)(ks * TOKENS + t)) * OUT_F + col);
            #pragma unroll
            for (int j = 0; j < 8; ++j) a[j] += (float)v[j];
        }
        #pragma unroll
        for (int j = 0; j < 8; ++j) s[PAD(col + j)] = a[j];
    }
    __syncthreads();
    fwht8192_lds(s, tid);
    const float sc = INV_SQRT_8192 * wscale[0];
    #pragma unroll
    for (int i = tid; i < OUT_F; i += 256)
        out[t * OUT_F + i] = s[PAD(i)] * sc * sv[i];
}

extern "C" void kernel_launch(void* const* d_in, const int* in_sizes, int n_in,
                              void* d_out, int out_size, void* d_ws, size_t ws_size,
                              hipStream_t stream) {
    const float* x      = (const float*)d_in[0];   // (32, 8192)
    const float* cb     = (const float*)d_in[1];   // (65536, 8)
    const int*   qidxs  = (const int*)d_in[2];     // (8192, 1024)
    const float* su     = (const float*)d_in[3];   // (8192,)
    const float* sv     = (const float*)d_in[4];   // (8192,)
    const float* wscale = (const float*)d_in[5];   // scalar
    float* out = (float*)d_out;                    // (32, 8192) fp32

    char* ws = (char*)d_ws;
    __bf16* cb_bf16 = (__bf16*)ws;                               // 1 MB
    __bf16* xh      = (__bf16*)(ws + (1u << 20));                // 512 KB
    __bf16* zpart   = (__bf16*)(ws + (1u << 20) + (512u << 10)); // 4 MB bf16

    hipLaunchKernelGGL(prep_kernel, dim3(544), dim3(256), 0, stream,
                       cb, cb_bf16, x, su, xh);
    hipLaunchKernelGGL(qgemm_kernel, dim3(32 * KSPLIT), dim3(512), 0, stream,
                       qidxs, cb_bf16, xh, zpart);
    hipLaunchKernelGGL(zsum_kernel, dim3(TOKENS), dim3(256), 0, stream,
                       zpart, sv, wscale, out);
}